// Round 8
// baseline (397.416 us; speedup 1.0000x reference)
//
#include <hip/hip_runtime.h>
#include <hip/hip_fp16.h>

#define N_NODES 50000
#define N_EDGES 800000
#define DIM 128
#define NUM_GRAPHS 128
#define STRIDE 64                      // CSR slot stride (>= max in-degree)
#define PSLICE 6272                    // padded nodes/slice (392 x 128 B lines)

#define ATTR_SCALE 33554432.0f         // 2^25 fixed-point for attr sums
#define ATTR_MASK  ((1ull << 40) - 1)

typedef _Float16 f16x8 __attribute__((ext_vector_type(8)));
typedef float f32x4 __attribute__((ext_vector_type(4)));

// ===========================================================================
// H / A layout (R15): COLUMN-PLANE-BLOCKED fp16 (4 planes of [n][64 B]).
// R16 (NT epack): REGRESSED — killed cross-cg L2 reuse. Plain loads.
// R17 (16-wide gather): NEUTRAL — not latency-bound.
// R18 (slice-grouped packed): NULL — atomics execute memory-side. Kept.
// R19 (un-sliced build): NULL — build bound by the 800K atomic RMWs
//   (~17 G atomics/s), invariant across structures. Sliced form kept.
// R20 (LDS-decoded gather): NEUTRAL — kept (decode-once enables R21).
// R21 (gemm1 fused into build): +2 us only. Counters showed why: gemm
//   blocks were FRONT-LOADED (grid = [gemm][csr]) -> they all finished in
//   the first ~10 us, then the 50 us atomic tail ran with MFMA back at 0
//   (MfmaUtil 0.8% over the kernel).
// R22: INTERLEAVED block map. Every 32nd blockIdx is a gemm block (782
//   slots spread across the first 25,024 indices), rest map 1:1 to CSR /
//   transpose in order. Keeps gemm waves co-resident with the atomic-bound
//   CSR waves for the whole drain (m114 mechanism: different pipes -> max,
//   not sum).
// ===========================================================================

__device__ __forceinline__ int pidx(int d) {
    return (d & 7) * PSLICE + (d >> 3);
}

// ===== fused: gemm1 (unscaled) + CSR build + Wt1 transpose, interleaved ====

__global__ __launch_bounds__(256) void k_build(const float* __restrict__ x,
                                               const int* __restrict__ src,
                                               const int* __restrict__ dst,
                                               const float* __restrict__ attr,
                                               const float* __restrict__ W0,
                                               const float* __restrict__ W1,
                                               unsigned long long* packed,
                                               unsigned int* __restrict__ epack,
                                               _Float16* __restrict__ Wt1,
                                               __half* __restrict__ H,
                                               int E, int nbChunks, int nbGemm, int n) {
    // quarter-tile of W0^T: WtL[col n][kk] = W0[c*32+kk][n], kk<32, pad to 40
    __shared__ _Float16 WtL[128 * 40];   // 10,240 B
    int b = blockIdx.x;
    int tid = threadIdx.x;

    int g = b >> 5;
    bool isGemm = ((b & 31) == 0) && (g < nbGemm);

    if (isGemm) {
        // ---------- gemm1 path: H'' = x @ W0 (fp16, plane-blocked, NO dv) --
        int w = tid >> 6, lane = tid & 63;
        int n15 = lane & 15, quad = lane >> 4;
        int node = g * 64 + w * 16 + n15;
        int nodec = node < n ? node : n - 1;
        const float* Arow = x + (size_t)nodec * DIM;

        f32x4 acc[8];
#pragma unroll
        for (int t = 0; t < 8; t++) acc[t] = (f32x4){0.f, 0.f, 0.f, 0.f};

        for (int c = 0; c < 4; c++) {
            __syncthreads();   // protect previous quarter's readers
            {
                int sn = tid & 127, kh = tid >> 7;   // 2 k-rows per pass
#pragma unroll
                for (int it = 0; it < 16; it++) {
                    int kk = kh + it * 2;
                    WtL[sn * 40 + kk] = (_Float16)W0[(size_t)(c * 32 + kk) * 128 + sn];
                }
            }
            __syncthreads();
            f16x8 bf;
            float4 a0 = ((const float4*)Arow)[c * 8 + quad * 2];
            float4 a1 = ((const float4*)Arow)[c * 8 + quad * 2 + 1];
            bf[0] = (_Float16)a0.x; bf[1] = (_Float16)a0.y;
            bf[2] = (_Float16)a0.z; bf[3] = (_Float16)a0.w;
            bf[4] = (_Float16)a1.x; bf[5] = (_Float16)a1.y;
            bf[6] = (_Float16)a1.z; bf[7] = (_Float16)a1.w;
#pragma unroll
            for (int t = 0; t < 8; t++) {
                f16x8 af = *(const f16x8*)(WtL + (t * 16 + n15) * 40 + quad * 8);
                acc[t] = __builtin_amdgcn_mfma_f32_16x16x32_f16(af, bf, acc[t], 0, 0, 0);
            }
        }

        if (node < n) {
            uint2* Hb = (uint2*)H;
#pragma unroll
            for (int t = 0; t < 8; t++) {
                __half2 h01 = __floats2half2_rn(acc[t][0], acc[t][1]);
                __half2 h23 = __floats2half2_rn(acc[t][2], acc[t][3]);
                uint2 pkd;
                pkd.x = *reinterpret_cast<unsigned int*>(&h01);
                pkd.y = *reinterpret_cast<unsigned int*>(&h23);
                int colq = quad + 4 * t;
                Hb[((size_t)(colq >> 3) * n + node) * 8 + (colq & 7)] = pkd;
            }
        }
        return;
    }

    // non-gemm: rank among non-gemm blocks (gemm slots at 0,32,... < nbGemm*32)
    int before = min(nbGemm, (b + 31) >> 5);
    int rest = b - before;

    if (rest >= nbChunks * 8) {
        // ---------- Wt1 transpose (16384 elements over 64 blocks) ----------
        int idx = (rest - nbChunks * 8) * 256 + tid;
        int nn = idx >> 7;
        int kk = idx & 127;
        Wt1[(size_t)nn * 128 + kk] = (_Float16)W1[(size_t)kk * 128 + nn];
        return;
    }

    // ---------- CSR path (XCD-sliced, R4 state) ----------------------------
    int slice = rest & 7;
    int e = (rest >> 3) * 256 + tid;
    if (e >= E) return;
    int d = dst[e];
    if ((d & 7) != slice) return;
    float a = attr[e];
    unsigned long long add =
        (1ull << 40) | (unsigned long long)(unsigned int)(a * ATTR_SCALE + 0.5f);
    unsigned long long old = atomicAdd(&packed[pidx(d)], add);
    int rank = (int)(old >> 40);
    if (rank < STRIDE) {
        __half ha = __float2half_rn(a);
        unsigned short us = *reinterpret_cast<unsigned short*>(&ha);
        epack[d * STRIDE + rank] = ((unsigned int)us << 16) | (unsigned int)src[e];
    }
}

// ===== dinv materialization (after build, before gather1) ==================

__global__ __launch_bounds__(256) void k_dinv(const unsigned long long* __restrict__ packed,
                                              float* __restrict__ dinv, int n) {
    int i = blockIdx.x * 256 + threadIdx.x;
    if (i < n) {
        unsigned long long pk = packed[pidx(i)];
        dinv[i] = rsqrtf(1.0f + (float)(pk & ATTR_MASK) * (1.0f / ATTR_SCALE));
    }
}

// ===== MFMA f16 GEMM, operand-swapped (layer 2 only now) ===================
// A = bufA16, PLANE-BLOCKED; dv applied in epilogue (packed available).

template <typename AT>
__global__ __launch_bounds__(256) void k_gemm_mfma(const AT* __restrict__ A,
                                                   const _Float16* __restrict__ Wt,
                                                   const unsigned long long* __restrict__ packed,
                                                   __half* __restrict__ H, int n) {
    int tid = threadIdx.x;
    int w = tid >> 6, lane = tid & 63;
    int n15 = lane & 15, quad = lane >> 4;
    int node = blockIdx.x * 64 + w * 16 + n15;
    int nodec = node < n ? node : n - 1;
    const AT* Arow = A + (size_t)nodec * DIM;   // used by float path only

    f32x4 acc[8];
#pragma unroll
    for (int t = 0; t < 8; t++) acc[t] = (f32x4){0.f, 0.f, 0.f, 0.f};

#pragma unroll
    for (int c = 0; c < 4; c++) {
        f16x8 bf;
        if constexpr (__is_same(AT, float)) {
            float4 a0 = ((const float4*)Arow)[c * 8 + quad * 2];
            float4 a1 = ((const float4*)Arow)[c * 8 + quad * 2 + 1];
            bf[0] = (_Float16)a0.x; bf[1] = (_Float16)a0.y;
            bf[2] = (_Float16)a0.z; bf[3] = (_Float16)a0.w;
            bf[4] = (_Float16)a1.x; bf[5] = (_Float16)a1.y;
            bf[6] = (_Float16)a1.z; bf[7] = (_Float16)a1.w;
        } else {
            const uint2* Ab = reinterpret_cast<const uint2*>(A);
            bf = *(const f16x8*)&Ab[((size_t)c * n + nodec) * 8 + quad * 2];
        }
#pragma unroll
        for (int t = 0; t < 8; t++) {
            f16x8 af = *(const f16x8*)(Wt + (size_t)(t * 16 + n15) * 128 + c * 32 + quad * 8);
            acc[t] = __builtin_amdgcn_mfma_f32_16x16x32_f16(af, bf, acc[t], 0, 0, 0);
        }
    }

    if (node < n) {
        unsigned long long pk = packed[pidx(nodec)];
        float dv = rsqrtf(1.0f + (float)(pk & ATTR_MASK) * (1.0f / ATTR_SCALE));
        uint2* Hb = (uint2*)H;
#pragma unroll
        for (int t = 0; t < 8; t++) {
            __half2 h01 = __floats2half2_rn(acc[t][0] * dv, acc[t][1] * dv);
            __half2 h23 = __floats2half2_rn(acc[t][2] * dv, acc[t][3] * dv);
            uint2 pkd;
            pkd.x = *reinterpret_cast<unsigned int*>(&h01);
            pkd.y = *reinterpret_cast<unsigned int*>(&h23);
            int colq = quad + 4 * t;
            Hb[((size_t)(colq >> 3) * n + node) * 8 + (colq & 7)] = pkd;
        }
    }
}

// ===== COLUMN-SLICED gather, plane-blocked H, LDS-decoded ==================
// SRCS=true (layer 1): H is unscaled; fold dinv[s] into wt in phase 1 and
// scale the self term by dv at init. SRCS=false (layer 2): dv pre-applied.

__device__ __forceinline__ float2 unpack_h2(unsigned int u) {
    __half2 h = *reinterpret_cast<__half2*>(&u);
    return __half22float2(h);
}

template <bool POOL, bool SRCS>
__global__ __launch_bounds__(256) void k_gather(const __half* __restrict__ H,
                                                const unsigned long long* __restrict__ packed,
                                                const unsigned int* __restrict__ epack,
                                                const float* __restrict__ dinv_arr,
                                                const float* __restrict__ bias,
                                                const int* __restrict__ batch,
                                                __half* __restrict__ OUT,
                                                float* gsum, float* cnt, int n) {
    int cg = blockIdx.x & 3;           // column group == plane (XCD-affine)
    int nb = blockIdx.x >> 2;          // node-block (32 nodes)
    int tid = threadIdx.x;

    // [k][slot] pre-decoded edges: .x = src_node*8 (uint2 idx), .y = wt bits
    __shared__ uint2 elds[STRIDE * 32];     // 16 KB
    __shared__ float dv_lds[32];
    __shared__ int   cr_lds[32];

    // ---- phase 1: cooperative decode, one thread per (slot, k-lane) ----
    {
        int slot = tid & 31;
        int kb = tid >> 5;                 // 0..7
        int i1 = nb * 32 + slot;
        int ic1 = (i1 < n) ? i1 : n - 1;
        unsigned long long pk = packed[pidx(ic1)];
        int ce = (i1 < n) ? (int)(pk >> 40) : 0;
        if (ce > STRIDE) ce = STRIDE;
        int cr = (ce + 7) & ~7;            // rounded up to 8
        if (kb == 0) {
            cr_lds[slot] = cr;
            dv_lds[slot] = rsqrtf(1.0f + (float)(pk & ATTR_MASK) * (1.0f / ATTR_SCALE));
        }
        const unsigned int* ep = epack + ic1 * STRIDE;
        for (int k = kb; k < cr; k += 8) {
            // padding slots decode pe=0 -> s=0 (valid row), wt=+0.0 (exact 0)
            unsigned int pe = (k < ce) ? ep[k] : 0u;
            __half_raw hr;
            hr.x = (unsigned short)(pe >> 16);
            float wv = __half2float(__half(hr));
            if (SRCS) wv *= dinv_arr[pe & 0xffffu];   // fold dinv_s (0*d=0 ok)
            elds[k * 32 + slot] = make_uint2((pe & 0xffffu) * 8u, __float_as_uint(wv));
        }
    }
    __syncthreads();

    // ---- phase 2: 8 lanes/node stream pre-decoded edges ----
    int slot = tid >> 3;               // node slot [0,32)
    int ln = tid & 7;                  // lane in group [0,8)
    int i = nb * 32 + slot;
    bool valid = i < n;
    int ic = valid ? i : n - 1;
    int colq = cg * 8 + ln;            // logical uint2 column [0,32) (bias/pool)
    const uint2* Hp = (const uint2*)H + (size_t)cg * n * 8;   // this cg's plane

    float dv = dv_lds[slot];
    int cr = cr_lds[slot];

    uint2 selfraw = Hp[(size_t)ic * 8 + ln];
    float2 s01 = unpack_h2(selfraw.x);
    float2 s23 = unpack_h2(selfraw.y);
    float4 acc = make_float4(s01.x, s01.y, s23.x, s23.y);
    if (SRCS) {                        // self term: dv * h''_i (then *dv at end)
        acc.x *= dv; acc.y *= dv; acc.z *= dv; acc.w *= dv;
    }

    for (int j = 0; j < cr; j += 8) {
        uint2 e[8];
#pragma unroll
        for (int k = 0; k < 8; k++) e[k] = elds[(j + k) * 32 + slot];  // broadcast
        uint2 v[8];
#pragma unroll
        for (int k = 0; k < 8; k++) v[k] = Hp[e[k].x + ln];
#pragma unroll
        for (int k = 0; k < 8; k++) {
            float wt = __uint_as_float(e[k].y);
            float2 f01 = unpack_h2(v[k].x);
            float2 f23 = unpack_h2(v[k].y);
            acc.x += wt * f01.x;
            acc.y += wt * f01.y;
            acc.z += wt * f23.x;
            acc.w += wt * f23.y;
        }
    }

    float4 bb = ((const float4*)bias)[colq];
    acc.x = fmaxf(acc.x * dv + bb.x, 0.f);
    acc.y = fmaxf(acc.y * dv + bb.y, 0.f);
    acc.z = fmaxf(acc.z * dv + bb.z, 0.f);
    acc.w = fmaxf(acc.w * dv + bb.w, 0.f);

    if constexpr (POOL) {
        __shared__ float lpool[32 * 32];  // 32 nodes x 32 feats (this cg)
        __shared__ int sg[32];
        __shared__ int meta[4];           // gA, gB, cntA, cntB
        if (ln == 0) sg[slot] = valid ? batch[ic] : -1;
        __syncthreads();
        if (tid == 0) {
            int nv = n - nb * 32; if (nv > 32) nv = 32;
            int gA = sg[0];
            int gB = sg[nv - 1];
            int cA = 0, cB = 0;
            for (int k2 = 0; k2 < nv; k2++) {
                if (sg[k2] == gA) cA++;
                else if (sg[k2] == gB) cB++;
            }
            meta[0] = gA; meta[1] = gB; meta[2] = cA; meta[3] = cB;
        }
        __syncthreads();
        int gA = meta[0], gB = meta[1];
        int myg = valid ? sg[slot] : -2;

        bool inA = valid && (myg == gA);
        ((float4*)(lpool + slot * 32))[ln] =
            inA ? acc : make_float4(0.f, 0.f, 0.f, 0.f);
        __syncthreads();
        if (tid < 32) {
            float ssum = 0.f;
#pragma unroll
            for (int k2 = 0; k2 < 32; k2++) ssum += lpool[k2 * 32 + tid];
            atomicAdd(&gsum[gA * DIM + cg * 32 + tid], ssum);
        }
        if (tid == 0 && cg == 0) atomicAdd(&cnt[gA], (float)meta[2]);

        if (gB != gA) {
            __syncthreads();
            bool inB = valid && (myg == gB);
            ((float4*)(lpool + slot * 32))[ln] =
                inB ? acc : make_float4(0.f, 0.f, 0.f, 0.f);
            __syncthreads();
            if (tid < 32) {
                float ssum = 0.f;
#pragma unroll
                for (int k2 = 0; k2 < 32; k2++) ssum += lpool[k2 * 32 + tid];
                atomicAdd(&gsum[gB * DIM + cg * 32 + tid], ssum);
            }
            if (tid == 0 && cg == 0) atomicAdd(&cnt[gB], (float)meta[3]);
        }

        if (valid && myg != gA && myg != gB) {
            float* o = gsum + (size_t)myg * DIM + cg * 32 + ln * 4;
            atomicAdd(o + 0, acc.x);
            atomicAdd(o + 1, acc.y);
            atomicAdd(o + 2, acc.z);
            atomicAdd(o + 3, acc.w);
            if (ln == 0 && cg == 0) atomicAdd(&cnt[myg], 1.0f);
        }
    } else {
        if (valid) {
            __half2 p01 = __floats2half2_rn(acc.x, acc.y);
            __half2 p23 = __floats2half2_rn(acc.z, acc.w);
            uint2 o;
            o.x = *reinterpret_cast<unsigned int*>(&p01);
            o.y = *reinterpret_cast<unsigned int*>(&p23);
            // plane-blocked output (consumed by k_gemm_mfma<_Float16>)
            ((uint2*)OUT)[((size_t)cg * n + i) * 8 + ln] = o;
        }
    }
}

// ================= classifier =================

__global__ __launch_bounds__(128) void k_classifier(const float* __restrict__ gsum,
                                                    const float* __restrict__ cnt,
                                                    const float* __restrict__ Wc1,
                                                    const float* __restrict__ bc1,
                                                    const float* __restrict__ Wc2,
                                                    const float* __restrict__ bc2,
                                                    float* __restrict__ out) {
    int g = blockIdx.x;
    int t = threadIdx.x;  // 128
    __shared__ float gv[128];
    __shared__ float hid[128];
    float inv = 1.0f / fmaxf(cnt[g], 1.0f);
    gv[t] = gsum[(size_t)g * DIM + t] * inv;
    __syncthreads();
    float acc = bc1[t];
    for (int k = 0; k < 128; k++) acc += gv[k] * Wc1[k * 128 + t];
    hid[t] = fmaxf(acc, 0.f);
    __syncthreads();
    if (t < 4) {
        float o = bc2[t];
        for (int k = 0; k < 128; k++) o += hid[k] * Wc2[k * 4 + t];
        out[g * 4 + t] = o;
    }
}

// ================= launch =================

extern "C" void kernel_launch(void* const* d_in, const int* in_sizes, int n_in,
                              void* d_out, int out_size, void* d_ws, size_t ws_size,
                              hipStream_t stream) {
    const float* x     = (const float*)d_in[0];
    const int*   ei    = (const int*)d_in[1];  // [2, E]: src then dst
    const float* attr  = (const float*)d_in[2];
    // d_in[3] edge_weight: unused by reference
    const int*   batch = (const int*)d_in[4];
    const float* W0  = (const float*)d_in[5];
    const float* b0  = (const float*)d_in[6];
    const float* W1  = (const float*)d_in[7];
    const float* b1  = (const float*)d_in[8];
    const float* Wc1 = (const float*)d_in[9];
    const float* bc1 = (const float*)d_in[10];
    const float* Wc2 = (const float*)d_in[11];
    const float* bc2 = (const float*)d_in[12];
    float* out = (float*)d_out;

    char* ws = (char*)d_ws;
    __half*             bufH16 = (__half*)(ws + 0);                  // 12,800,000
    __half*             bufA16 = (__half*)(ws + 12800000);           // 12,800,000
    unsigned int*       epack  = (unsigned int*)(ws + 25600000);     // 12,800,000
    unsigned long long* packed = (unsigned long long*)(ws + 38400000);  // 8*6272*8 = 401,408
    float*              gsum   = (float*)(ws + 38801408);            //     65,536
    float*              cnt    = (float*)(ws + 38866944);            //        512
    _Float16*           Wt1    = (_Float16*)(ws + 38867456);         //     32,768
    float*              dinv   = (float*)(ws + 38900224);            //    200,000

    const int* src = ei;
    const int* dst = ei + N_EDGES;

    const int NB_C = (N_EDGES + 255) / 256;            // 3125 chunks
    const int NB_G = ((N_NODES + 31) / 32) * 4;        // 1563 node-blocks x 4 cg
    const int NB_M = (N_NODES + 63) / 64;              // 782
    const int NB_D = (N_NODES + 255) / 256;            // 196

    // zero packed+gsum+cnt (contiguous 467,456 B) without a kernel launch
    (void)hipMemsetAsync(ws + 38400000, 0, 467456, stream);

    // fused + interleaved: gemm1 (every 32nd block) + CSR build + Wt1 transpose
    k_build<<<NB_M + NB_C * 8 + 64, 256, 0, stream>>>(x, src, dst, attr, W0, W1,
                                                      packed, epack, Wt1, bufH16,
                                                      N_EDGES, NB_C, NB_M, N_NODES);

    // dinv materialization (tiny)
    k_dinv<<<NB_D, 256, 0, stream>>>(packed, dinv, N_NODES);

    // layer 1 gather: folds dinv_s into wt, dv on self + epilogue
    k_gather<false, true><<<NB_G, 256, 0, stream>>>(bufH16, packed, epack, dinv,
                                                    b0, batch, bufA16, gsum, cnt,
                                                    N_NODES);

    // layer 2: MFMA gemm (fp16 plane-blocked A, dv in epilogue) + gather/pool
    k_gemm_mfma<_Float16><<<NB_M, 256, 0, stream>>>((const _Float16*)bufA16, Wt1,
                                                    packed, bufH16, N_NODES);
    k_gather<true, false><<<NB_G, 256, 0, stream>>>(bufH16, packed, epack, dinv,
                                                    b1, batch, nullptr, gsum, cnt,
                                                    N_NODES);

    // classifier
    k_classifier<<<NUM_GRAPHS, 128, 0, stream>>>(gsum, cnt, Wc1, bc1, Wc2, bc2, out);
}

// Round 9
// 256.992 us; speedup vs baseline: 1.5464x; 1.5464x over previous
//
#include <hip/hip_runtime.h>
#include <hip/hip_fp16.h>

#define N_NODES 50000
#define N_EDGES 800000
#define DIM 128
#define NUM_GRAPHS 128
#define STRIDE 64                      // CSR slot stride (>= max in-degree)
#define PSLICE 6272                    // padded nodes/slice (392 x 128 B lines)
#define GEMM_OCTS 98                   // ceil(782/8) gemm octets
#define OCT_SPACING 33                 // one gemm octet every 33 octets

#define ATTR_SCALE 33554432.0f         // 2^25 fixed-point for attr sums
#define ATTR_MASK  ((1ull << 40) - 1)

typedef _Float16 f16x8 __attribute__((ext_vector_type(8)));
typedef float f32x4 __attribute__((ext_vector_type(4)));

// ===========================================================================
// H / A layout (R15): COLUMN-PLANE-BLOCKED fp16 (4 planes of [n][64 B]).
// R16 (NT epack): REGRESSED — killed cross-cg L2 reuse. Plain loads.
// R17 (16-wide gather): NEUTRAL — not latency-bound.
// R18 (slice-grouped packed): NULL — atomics execute memory-side. Kept.
// R19 (un-sliced build): NULL — build bound by the 800K atomic RMWs. Sliced
//   form kept (epack write locality).
// R20 (LDS-decoded gather): NEUTRAL — kept.
// R21 (gemm1 fused into build, front-loaded): +2 us only — gemm blocks all
//   finished in the first ~10 us; atomic tail ran with MFMA at 0.
// R22 (every-32nd interleave): REGRESSED 4x. blockIdx->XCD is round-robin
//   mod 8; slots at b%32==0 all hit ONE XCD -> 782 gemm blocks serialized
//   on 32 CUs (occupancy 13% ~= 1/8). Also broke slice==b&7 epack-write
//   affinity (WRITE 46->60 MB).
// R23: OCTET-ALIGNED interleave. Gemm inserted as aligned runs of 8
//   consecutive blocks (one per XCD), one octet every OCT_SPACING octets.
//   rest = b - 8*(gemm octets before) keeps rest%8 == b%8 -> slice/XCD
//   affinity preserved; gemm work spread evenly over the atomic drain.
// ===========================================================================

__device__ __forceinline__ int pidx(int d) {
    return (d & 7) * PSLICE + (d >> 3);
}

// ===== fused: gemm1 (unscaled) + CSR build + Wt1 transpose, octet map ======

__global__ __launch_bounds__(256) void k_build(const float* __restrict__ x,
                                               const int* __restrict__ src,
                                               const int* __restrict__ dst,
                                               const float* __restrict__ attr,
                                               const float* __restrict__ W0,
                                               const float* __restrict__ W1,
                                               unsigned long long* packed,
                                               unsigned int* __restrict__ epack,
                                               _Float16* __restrict__ Wt1,
                                               __half* __restrict__ H,
                                               int E, int nbChunks, int nbGemm, int n) {
    // quarter-tile of W0^T: WtL[col n][kk] = W0[c*32+kk][n], kk<32, pad to 40
    __shared__ _Float16 WtL[128 * 40];   // 10,240 B
    int b = blockIdx.x;
    int tid = threadIdx.x;

    int p = b >> 3;                    // octet index
    int w8 = b & 7;                    // position in octet (XCD-affine)
    int pq = p / OCT_SPACING;
    int pr = p - pq * OCT_SPACING;
    bool isGemmOct = (pr == 0) && (pq < GEMM_OCTS);

    if (isGemmOct) {
        int g = pq * 8 + w8;           // gemm block id, one per XCD per octet
        if (g >= nbGemm) return;       // 784-782 = 2 idle slots
        // ---------- gemm1 path: H'' = x @ W0 (fp16, plane-blocked, NO dv) --
        int w = tid >> 6, lane = tid & 63;
        int n15 = lane & 15, quad = lane >> 4;
        int node = g * 64 + w * 16 + n15;
        int nodec = node < n ? node : n - 1;
        const float* Arow = x + (size_t)nodec * DIM;

        f32x4 acc[8];
#pragma unroll
        for (int t = 0; t < 8; t++) acc[t] = (f32x4){0.f, 0.f, 0.f, 0.f};

        for (int c = 0; c < 4; c++) {
            __syncthreads();   // protect previous quarter's readers
            {
                int sn = tid & 127, kh = tid >> 7;   // 2 k-rows per pass
#pragma unroll
                for (int it = 0; it < 16; it++) {
                    int kk = kh + it * 2;
                    WtL[sn * 40 + kk] = (_Float16)W0[(size_t)(c * 32 + kk) * 128 + sn];
                }
            }
            __syncthreads();
            f16x8 bf;
            float4 a0 = ((const float4*)Arow)[c * 8 + quad * 2];
            float4 a1 = ((const float4*)Arow)[c * 8 + quad * 2 + 1];
            bf[0] = (_Float16)a0.x; bf[1] = (_Float16)a0.y;
            bf[2] = (_Float16)a0.z; bf[3] = (_Float16)a0.w;
            bf[4] = (_Float16)a1.x; bf[5] = (_Float16)a1.y;
            bf[6] = (_Float16)a1.z; bf[7] = (_Float16)a1.w;
#pragma unroll
            for (int t = 0; t < 8; t++) {
                f16x8 af = *(const f16x8*)(WtL + (t * 16 + n15) * 40 + quad * 8);
                acc[t] = __builtin_amdgcn_mfma_f32_16x16x32_f16(af, bf, acc[t], 0, 0, 0);
            }
        }

        if (node < n) {
            uint2* Hb = (uint2*)H;
#pragma unroll
            for (int t = 0; t < 8; t++) {
                __half2 h01 = __floats2half2_rn(acc[t][0], acc[t][1]);
                __half2 h23 = __floats2half2_rn(acc[t][2], acc[t][3]);
                uint2 pkd;
                pkd.x = *reinterpret_cast<unsigned int*>(&h01);
                pkd.y = *reinterpret_cast<unsigned int*>(&h23);
                int colq = quad + 4 * t;
                Hb[((size_t)(colq >> 3) * n + node) * 8 + (colq & 7)] = pkd;
            }
        }
        return;
    }

    // non-gemm: gemm octets before p = pq+1 (since pr>0); multiples of 8
    // subtracted -> rest%8 == b%8 (slice/XCD affinity preserved)
    int rest = (p - pq - 1) * 8 + w8;

    if (rest >= nbChunks * 8) {
        // ---------- Wt1 transpose (16384 elements over 64 blocks) ----------
        int idx = (rest - nbChunks * 8) * 256 + tid;
        int nn = idx >> 7;
        int kk = idx & 127;
        Wt1[(size_t)nn * 128 + kk] = (_Float16)W1[(size_t)kk * 128 + nn];
        return;
    }

    // ---------- CSR path (XCD-sliced, R4 state) ----------------------------
    int slice = rest & 7;
    int e = (rest >> 3) * 256 + tid;
    if (e >= E) return;
    int d = dst[e];
    if ((d & 7) != slice) return;
    float a = attr[e];
    unsigned long long add =
        (1ull << 40) | (unsigned long long)(unsigned int)(a * ATTR_SCALE + 0.5f);
    unsigned long long old = atomicAdd(&packed[pidx(d)], add);
    int rank = (int)(old >> 40);
    if (rank < STRIDE) {
        __half ha = __float2half_rn(a);
        unsigned short us = *reinterpret_cast<unsigned short*>(&ha);
        epack[d * STRIDE + rank] = ((unsigned int)us << 16) | (unsigned int)src[e];
    }
}

// ===== dinv materialization (after build, before gather1) ==================

__global__ __launch_bounds__(256) void k_dinv(const unsigned long long* __restrict__ packed,
                                              float* __restrict__ dinv, int n) {
    int i = blockIdx.x * 256 + threadIdx.x;
    if (i < n) {
        unsigned long long pk = packed[pidx(i)];
        dinv[i] = rsqrtf(1.0f + (float)(pk & ATTR_MASK) * (1.0f / ATTR_SCALE));
    }
}

// ===== MFMA f16 GEMM, operand-swapped (layer 2 only now) ===================
// A = bufA16, PLANE-BLOCKED; dv applied in epilogue (packed available).

template <typename AT>
__global__ __launch_bounds__(256) void k_gemm_mfma(const AT* __restrict__ A,
                                                   const _Float16* __restrict__ Wt,
                                                   const unsigned long long* __restrict__ packed,
                                                   __half* __restrict__ H, int n) {
    int tid = threadIdx.x;
    int w = tid >> 6, lane = tid & 63;
    int n15 = lane & 15, quad = lane >> 4;
    int node = blockIdx.x * 64 + w * 16 + n15;
    int nodec = node < n ? node : n - 1;
    const AT* Arow = A + (size_t)nodec * DIM;   // used by float path only

    f32x4 acc[8];
#pragma unroll
    for (int t = 0; t < 8; t++) acc[t] = (f32x4){0.f, 0.f, 0.f, 0.f};

#pragma unroll
    for (int c = 0; c < 4; c++) {
        f16x8 bf;
        if constexpr (__is_same(AT, float)) {
            float4 a0 = ((const float4*)Arow)[c * 8 + quad * 2];
            float4 a1 = ((const float4*)Arow)[c * 8 + quad * 2 + 1];
            bf[0] = (_Float16)a0.x; bf[1] = (_Float16)a0.y;
            bf[2] = (_Float16)a0.z; bf[3] = (_Float16)a0.w;
            bf[4] = (_Float16)a1.x; bf[5] = (_Float16)a1.y;
            bf[6] = (_Float16)a1.z; bf[7] = (_Float16)a1.w;
        } else {
            const uint2* Ab = reinterpret_cast<const uint2*>(A);
            bf = *(const f16x8*)&Ab[((size_t)c * n + nodec) * 8 + quad * 2];
        }
#pragma unroll
        for (int t = 0; t < 8; t++) {
            f16x8 af = *(const f16x8*)(Wt + (size_t)(t * 16 + n15) * 128 + c * 32 + quad * 8);
            acc[t] = __builtin_amdgcn_mfma_f32_16x16x32_f16(af, bf, acc[t], 0, 0, 0);
        }
    }

    if (node < n) {
        unsigned long long pk = packed[pidx(nodec)];
        float dv = rsqrtf(1.0f + (float)(pk & ATTR_MASK) * (1.0f / ATTR_SCALE));
        uint2* Hb = (uint2*)H;
#pragma unroll
        for (int t = 0; t < 8; t++) {
            __half2 h01 = __floats2half2_rn(acc[t][0] * dv, acc[t][1] * dv);
            __half2 h23 = __floats2half2_rn(acc[t][2] * dv, acc[t][3] * dv);
            uint2 pkd;
            pkd.x = *reinterpret_cast<unsigned int*>(&h01);
            pkd.y = *reinterpret_cast<unsigned int*>(&h23);
            int colq = quad + 4 * t;
            Hb[((size_t)(colq >> 3) * n + node) * 8 + (colq & 7)] = pkd;
        }
    }
}

// ===== COLUMN-SLICED gather, plane-blocked H, LDS-decoded ==================
// SRCS=true (layer 1): H is unscaled; fold dinv[s] into wt in phase 1 and
// scale the self term by dv at init. SRCS=false (layer 2): dv pre-applied.

__device__ __forceinline__ float2 unpack_h2(unsigned int u) {
    __half2 h = *reinterpret_cast<__half2*>(&u);
    return __half22float2(h);
}

template <bool POOL, bool SRCS>
__global__ __launch_bounds__(256) void k_gather(const __half* __restrict__ H,
                                                const unsigned long long* __restrict__ packed,
                                                const unsigned int* __restrict__ epack,
                                                const float* __restrict__ dinv_arr,
                                                const float* __restrict__ bias,
                                                const int* __restrict__ batch,
                                                __half* __restrict__ OUT,
                                                float* gsum, float* cnt, int n) {
    int cg = blockIdx.x & 3;           // column group == plane (XCD-affine)
    int nb = blockIdx.x >> 2;          // node-block (32 nodes)
    int tid = threadIdx.x;

    // [k][slot] pre-decoded edges: .x = src_node*8 (uint2 idx), .y = wt bits
    __shared__ uint2 elds[STRIDE * 32];     // 16 KB
    __shared__ float dv_lds[32];
    __shared__ int   cr_lds[32];

    // ---- phase 1: cooperative decode, one thread per (slot, k-lane) ----
    {
        int slot = tid & 31;
        int kb = tid >> 5;                 // 0..7
        int i1 = nb * 32 + slot;
        int ic1 = (i1 < n) ? i1 : n - 1;
        unsigned long long pk = packed[pidx(ic1)];
        int ce = (i1 < n) ? (int)(pk >> 40) : 0;
        if (ce > STRIDE) ce = STRIDE;
        int cr = (ce + 7) & ~7;            // rounded up to 8
        if (kb == 0) {
            cr_lds[slot] = cr;
            dv_lds[slot] = rsqrtf(1.0f + (float)(pk & ATTR_MASK) * (1.0f / ATTR_SCALE));
        }
        const unsigned int* ep = epack + ic1 * STRIDE;
        for (int k = kb; k < cr; k += 8) {
            // padding slots decode pe=0 -> s=0 (valid row), wt=+0.0 (exact 0)
            unsigned int pe = (k < ce) ? ep[k] : 0u;
            __half_raw hr;
            hr.x = (unsigned short)(pe >> 16);
            float wv = __half2float(__half(hr));
            if (SRCS) wv *= dinv_arr[pe & 0xffffu];   // fold dinv_s (0*d=0 ok)
            elds[k * 32 + slot] = make_uint2((pe & 0xffffu) * 8u, __float_as_uint(wv));
        }
    }
    __syncthreads();

    // ---- phase 2: 8 lanes/node stream pre-decoded edges ----
    int slot = tid >> 3;               // node slot [0,32)
    int ln = tid & 7;                  // lane in group [0,8)
    int i = nb * 32 + slot;
    bool valid = i < n;
    int ic = valid ? i : n - 1;
    int colq = cg * 8 + ln;            // logical uint2 column [0,32) (bias/pool)
    const uint2* Hp = (const uint2*)H + (size_t)cg * n * 8;   // this cg's plane

    float dv = dv_lds[slot];
    int cr = cr_lds[slot];

    uint2 selfraw = Hp[(size_t)ic * 8 + ln];
    float2 s01 = unpack_h2(selfraw.x);
    float2 s23 = unpack_h2(selfraw.y);
    float4 acc = make_float4(s01.x, s01.y, s23.x, s23.y);
    if (SRCS) {                        // self term: dv * h''_i (then *dv at end)
        acc.x *= dv; acc.y *= dv; acc.z *= dv; acc.w *= dv;
    }

    for (int j = 0; j < cr; j += 8) {
        uint2 e[8];
#pragma unroll
        for (int k = 0; k < 8; k++) e[k] = elds[(j + k) * 32 + slot];  // broadcast
        uint2 v[8];
#pragma unroll
        for (int k = 0; k < 8; k++) v[k] = Hp[e[k].x + ln];
#pragma unroll
        for (int k = 0; k < 8; k++) {
            float wt = __uint_as_float(e[k].y);
            float2 f01 = unpack_h2(v[k].x);
            float2 f23 = unpack_h2(v[k].y);
            acc.x += wt * f01.x;
            acc.y += wt * f01.y;
            acc.z += wt * f23.x;
            acc.w += wt * f23.y;
        }
    }

    float4 bb = ((const float4*)bias)[colq];
    acc.x = fmaxf(acc.x * dv + bb.x, 0.f);
    acc.y = fmaxf(acc.y * dv + bb.y, 0.f);
    acc.z = fmaxf(acc.z * dv + bb.z, 0.f);
    acc.w = fmaxf(acc.w * dv + bb.w, 0.f);

    if constexpr (POOL) {
        __shared__ float lpool[32 * 32];  // 32 nodes x 32 feats (this cg)
        __shared__ int sg[32];
        __shared__ int meta[4];           // gA, gB, cntA, cntB
        if (ln == 0) sg[slot] = valid ? batch[ic] : -1;
        __syncthreads();
        if (tid == 0) {
            int nv = n - nb * 32; if (nv > 32) nv = 32;
            int gA = sg[0];
            int gB = sg[nv - 1];
            int cA = 0, cB = 0;
            for (int k2 = 0; k2 < nv; k2++) {
                if (sg[k2] == gA) cA++;
                else if (sg[k2] == gB) cB++;
            }
            meta[0] = gA; meta[1] = gB; meta[2] = cA; meta[3] = cB;
        }
        __syncthreads();
        int gA = meta[0], gB = meta[1];
        int myg = valid ? sg[slot] : -2;

        bool inA = valid && (myg == gA);
        ((float4*)(lpool + slot * 32))[ln] =
            inA ? acc : make_float4(0.f, 0.f, 0.f, 0.f);
        __syncthreads();
        if (tid < 32) {
            float ssum = 0.f;
#pragma unroll
            for (int k2 = 0; k2 < 32; k2++) ssum += lpool[k2 * 32 + tid];
            atomicAdd(&gsum[gA * DIM + cg * 32 + tid], ssum);
        }
        if (tid == 0 && cg == 0) atomicAdd(&cnt[gA], (float)meta[2]);

        if (gB != gA) {
            __syncthreads();
            bool inB = valid && (myg == gB);
            ((float4*)(lpool + slot * 32))[ln] =
                inB ? acc : make_float4(0.f, 0.f, 0.f, 0.f);
            __syncthreads();
            if (tid < 32) {
                float ssum = 0.f;
#pragma unroll
                for (int k2 = 0; k2 < 32; k2++) ssum += lpool[k2 * 32 + tid];
                atomicAdd(&gsum[gB * DIM + cg * 32 + tid], ssum);
            }
            if (tid == 0 && cg == 0) atomicAdd(&cnt[gB], (float)meta[3]);
        }

        if (valid && myg != gA && myg != gB) {
            float* o = gsum + (size_t)myg * DIM + cg * 32 + ln * 4;
            atomicAdd(o + 0, acc.x);
            atomicAdd(o + 1, acc.y);
            atomicAdd(o + 2, acc.z);
            atomicAdd(o + 3, acc.w);
            if (ln == 0 && cg == 0) atomicAdd(&cnt[myg], 1.0f);
        }
    } else {
        if (valid) {
            __half2 p01 = __floats2half2_rn(acc.x, acc.y);
            __half2 p23 = __floats2half2_rn(acc.z, acc.w);
            uint2 o;
            o.x = *reinterpret_cast<unsigned int*>(&p01);
            o.y = *reinterpret_cast<unsigned int*>(&p23);
            // plane-blocked output (consumed by k_gemm_mfma<_Float16>)
            ((uint2*)OUT)[((size_t)cg * n + i) * 8 + ln] = o;
        }
    }
}

// ================= classifier =================

__global__ __launch_bounds__(128) void k_classifier(const float* __restrict__ gsum,
                                                    const float* __restrict__ cnt,
                                                    const float* __restrict__ Wc1,
                                                    const float* __restrict__ bc1,
                                                    const float* __restrict__ Wc2,
                                                    const float* __restrict__ bc2,
                                                    float* __restrict__ out) {
    int g = blockIdx.x;
    int t = threadIdx.x;  // 128
    __shared__ float gv[128];
    __shared__ float hid[128];
    float inv = 1.0f / fmaxf(cnt[g], 1.0f);
    gv[t] = gsum[(size_t)g * DIM + t] * inv;
    __syncthreads();
    float acc = bc1[t];
    for (int k = 0; k < 128; k++) acc += gv[k] * Wc1[k * 128 + t];
    hid[t] = fmaxf(acc, 0.f);
    __syncthreads();
    if (t < 4) {
        float o = bc2[t];
        for (int k = 0; k < 128; k++) o += hid[k] * Wc2[k * 4 + t];
        out[g * 4 + t] = o;
    }
}

// ================= launch =================

extern "C" void kernel_launch(void* const* d_in, const int* in_sizes, int n_in,
                              void* d_out, int out_size, void* d_ws, size_t ws_size,
                              hipStream_t stream) {
    const float* x     = (const float*)d_in[0];
    const int*   ei    = (const int*)d_in[1];  // [2, E]: src then dst
    const float* attr  = (const float*)d_in[2];
    // d_in[3] edge_weight: unused by reference
    const int*   batch = (const int*)d_in[4];
    const float* W0  = (const float*)d_in[5];
    const float* b0  = (const float*)d_in[6];
    const float* W1  = (const float*)d_in[7];
    const float* b1  = (const float*)d_in[8];
    const float* Wc1 = (const float*)d_in[9];
    const float* bc1 = (const float*)d_in[10];
    const float* Wc2 = (const float*)d_in[11];
    const float* bc2 = (const float*)d_in[12];
    float* out = (float*)d_out;

    char* ws = (char*)d_ws;
    __half*             bufH16 = (__half*)(ws + 0);                  // 12,800,000
    __half*             bufA16 = (__half*)(ws + 12800000);           // 12,800,000
    unsigned int*       epack  = (unsigned int*)(ws + 25600000);     // 12,800,000
    unsigned long long* packed = (unsigned long long*)(ws + 38400000);  // 8*6272*8 = 401,408
    float*              gsum   = (float*)(ws + 38801408);            //     65,536
    float*              cnt    = (float*)(ws + 38866944);            //        512
    _Float16*           Wt1    = (_Float16*)(ws + 38867456);         //     32,768
    float*              dinv   = (float*)(ws + 38900224);            //    200,000

    const int* src = ei;
    const int* dst = ei + N_EDGES;

    const int NB_C = (N_EDGES + 255) / 256;            // 3125 chunks (octet-exact: 25000 blocks)
    const int NB_G = ((N_NODES + 31) / 32) * 4;        // 1563 node-blocks x 4 cg
    const int NB_M = (N_NODES + 63) / 64;              // 782
    const int NB_D = (N_NODES + 255) / 256;            // 196
    // total octets: 3125 CSR + 8 transpose + 98 gemm = 3231
    const int NB_F = (NB_C + 8 + GEMM_OCTS) * 8;       // 25,848 blocks

    // zero packed+gsum+cnt (contiguous 467,456 B) without a kernel launch
    (void)hipMemsetAsync(ws + 38400000, 0, 467456, stream);

    // fused, octet-interleaved: gemm1 + XCD-sliced CSR build + Wt1 transpose
    k_build<<<NB_F, 256, 0, stream>>>(x, src, dst, attr, W0, W1,
                                      packed, epack, Wt1, bufH16,
                                      N_EDGES, NB_C, NB_M, N_NODES);

    // dinv materialization (tiny)
    k_dinv<<<NB_D, 256, 0, stream>>>(packed, dinv, N_NODES);

    // layer 1 gather: folds dinv_s into wt, dv on self + epilogue
    k_gather<false, true><<<NB_G, 256, 0, stream>>>(bufH16, packed, epack, dinv,
                                                    b0, batch, bufA16, gsum, cnt,
                                                    N_NODES);

    // layer 2: MFMA gemm (fp16 plane-blocked A, dv in epilogue) + gather/pool
    k_gemm_mfma<_Float16><<<NB_M, 256, 0, stream>>>((const _Float16*)bufA16, Wt1,
                                                    packed, bufH16, N_NODES);
    k_gather<true, false><<<NB_G, 256, 0, stream>>>(bufH16, packed, epack, dinv,
                                                    b1, batch, nullptr, gsum, cnt,
                                                    N_NODES);

    // classifier
    k_classifier<<<NUM_GRAPHS, 128, 0, stream>>>(gsum, cnt, Wc1, bc1, Wc2, bc2, out);
}